// Round 16
// baseline (126.863 us; speedup 1.0000x reference)
//
#include <hip/hip_runtime.h>

typedef unsigned long long u64;
typedef unsigned short u16;
typedef unsigned u32;
typedef unsigned char u8;

#define PRE   2000
#define POST  300
#define NCLS  5
#define CAP   512
#define INF   0x7fffffff
#define MAGIC 0x13579BDFu
#define NBLK  86
#define SCAN0 80
#define SORTB 85

// Exact threshold midpoint: fl32(inter/uni) > 0.55f  <=>  inter >= MID*uni (uni>0).
// MID = 0.55f + 2^-25; MID*(24-bit uni) exact in f64 -> bit-exact predicate.
// Validated: absmax == 0.0 in rounds 3-15.
#define MID 0x1.19999A8p-1

template <int K> struct IC { static constexpr int v = K; };
template <int N, typename F> __device__ __forceinline__ void unrollN(F&& f) {
    if constexpr (N > 0) { unrollN<N - 1>(f); f(IC<N - 1>{}); }
}

__device__ __forceinline__ u32 aload_acq(u32* p) {
    return __hip_atomic_load(p, __ATOMIC_ACQUIRE, __HIP_MEMORY_SCOPE_AGENT);
}

__device__ __forceinline__ bool iou_pred(float bx0, float bx1, float bx2, float bx3,
                                         float a1, float m0, float m1, float m2, float m3,
                                         float a2) {
    const float ltx = fmaxf(bx0, m0), lty = fmaxf(bx1, m1);
    const float rbx = fminf(bx2, m2), rby = fminf(bx3, m3);
    const float wd = fmaxf(rbx - ltx, 0.f), hg = fmaxf(rby - lty, 0.f);
    const float inter = wd * hg;
    const float uni = (a1 + a2) - inter;
    return (uni > 0.f) && ((double)inter >= MID * (double)uni);
}

// Blocks 0-79: matrix (16 blocks/class, 4 rows/wave). Blocks 80-84: scan (one/class,
// overlap compaction+det-preload with matrix, 8-wave staging, wave0 serial scan).
// Block 85: sort. Spin barriers via device-scope ctrl counters.
__global__ __launch_bounds__(512, 1) void wbf_all(const float* __restrict__ x,
                                                  u64* __restrict__ M,
                                                  u32* __restrict__ ctrl,
                                                  float* __restrict__ recs,
                                                  int* __restrict__ cnts,
                                                  float* __restrict__ out) {
#pragma clang fp contract(off)
    __shared__ __align__(16) char s_buf[58448];
    u8*  s_mtx = (u8*)s_buf;                                 // 32768
    float (*s_det)[8]  = (float (*)[8])(s_buf + 32768);      // 16384
    float (*s_dov)[16] = (float (*)[16])(s_buf + 49152);     // 8192: dirty clusters
    u16* s_list        = (u16*)(s_buf + 57344);              // 1024
    u8*  s_ab          = (u8*)(s_buf + 58376);               // 64: shared alive bytes

    const int tid  = threadIdx.x;
    const int lane = tid & 63;
    const int wave = tid >> 6;
    const int b    = blockIdx.x;

    // ---- init handshake (ws re-poisoned 0xAA before every launch) ----
    if (b == 0) {
        if (tid == 0) {
            for (int i = 0; i < NCLS; ++i)
                __hip_atomic_store(&ctrl[i], 0u, __ATOMIC_RELAXED, __HIP_MEMORY_SCOPE_AGENT);
            __hip_atomic_store(&ctrl[16], 0u, __ATOMIC_RELAXED, __HIP_MEMORY_SCOPE_AGENT);
            __hip_atomic_store(&ctrl[32], MAGIC, __ATOMIC_RELEASE, __HIP_MEMORY_SCOPE_AGENT);
        }
    } else {
        if (tid == 0) { while (aload_acq(&ctrl[32]) != MAGIC) {} }
    }
    __syncthreads();

    // ================= SORT BLOCK =================
    if (b == SORTB) {
        u64* keys = (u64*)s_buf;             // 16384
        u32* hist = (u32*)(s_buf + 16384);   // 16384
        u64* cand = (u64*)(s_buf + 32768);   // 4096
        u32* part = (u32*)(s_buf + 36864);   // 2048
        int* scal = (int*)(s_buf + 38912);

        for (int i = tid; i < 2048; i += 512) keys[i] = ~0ull;
        for (int h = tid; h < 4096; h += 512) hist[h] = 0u;
        if (tid == 0) scal[2] = 0;
        __syncthreads();
        if (tid == 0) { while (aload_acq(&ctrl[16]) < (u32)NCLS) {} }
        __syncthreads();

        int c[NCLS], off[NCLS];
        int n = 0;
        #pragma unroll
        for (int w = 0; w < NCLS; ++w) { c[w] = cnts[w]; off[w] = n; n += c[w]; }
        if (n > 2048) n = 2048;

        #pragma unroll
        for (int w = 0; w < NCLS; ++w) {
            const int cw = c[w], ow = off[w];
            for (int j = tid; j < cw; j += 512) {
                const float* r = recs + (size_t)(w * CAP + j) * 8;
                const unsigned sb = __float_as_uint(r[4]);
                const int g = ((const int*)r)[5];
                const int id = w * CAP + j;
                u64 key = ((u64)sb << 32) | ((u64)(unsigned)(0xFFFF - g) << 16) | (u64)id;
                keys[ow + j] = ~key;
            }
        }
        __syncthreads();

        for (int i = tid; i < n; i += 512)
            atomicAdd(&hist[(u32)(keys[i] >> 52)], 1u);
        __syncthreads();

        const int target = (POST < n) ? POST : n;
        u32 p = 0;
        #pragma unroll
        for (int k = 0; k < 8; ++k) p += hist[tid * 8 + k];
        part[tid] = p;
        __syncthreads();
        for (int o2 = 1; o2 < 512; o2 <<= 1) {
            const u32 v = part[tid];
            const u32 add = (tid >= o2) ? part[tid - o2] : 0u;
            __syncthreads();
            part[tid] = v + add;
            __syncthreads();
        }
        const u32 I = part[tid];
        const u32 E = I - p;
        if ((int)E < target && (int)I >= target) { scal[0] = tid; scal[1] = (int)E; }
        __syncthreads();
        const int T = scal[0];
        int cum = scal[1];
        int B = T * 8 + 7;
        for (int bb = T * 8; bb < T * 8 + 8; ++bb) {
            const int h = (int)hist[bb];
            if (cum + h >= target) { B = bb; break; }
            cum += h;
        }
        const int candCount = cum + (int)hist[B];

        if (candCount <= 512) {
            for (int i = tid; i < n; i += 512) {
                const u64 kk = keys[i];
                if ((int)(u32)(kk >> 52) <= B) {
                    const int pos = atomicAdd(&scal[2], 1);
                    cand[pos] = kk;
                }
            }
            __syncthreads();
            if (tid >= candCount) cand[tid] = ~0ull;
            __syncthreads();
            for (int kk2 = 2; kk2 <= 512; kk2 <<= 1) {
                for (int jj = kk2 >> 1; jj > 0; jj >>= 1) {
                    const int i = tid, ixj = i ^ jj;
                    if (ixj > i) {
                        const u64 a = cand[i], bb2 = cand[ixj];
                        const bool up = ((i & kk2) == 0);
                        if ((a > bb2) == up) { cand[i] = bb2; cand[ixj] = a; }
                    }
                    __syncthreads();
                }
            }
            if (tid < POST) {
                float* o = out + tid * 6;
                if (tid < target) {
                    const u64 key = ~cand[tid];
                    const int id = (int)(key & 0xFFFFull);
                    const float* rec = recs + (size_t)id * 8;
                    o[0] = rec[0]; o[1] = rec[1]; o[2] = rec[2]; o[3] = rec[3];
                    o[4] = __uint_as_float((unsigned)(key >> 32));
                    o[5] = (float)(id >> 9);
                } else {
                    o[0] = 0.f; o[1] = 0.f; o[2] = 0.f; o[3] = 0.f; o[4] = 0.f; o[5] = 0.f;
                }
            }
        } else {
            for (int kk2 = 2; kk2 <= 2048; kk2 <<= 1) {
                for (int jj = kk2 >> 1; jj > 0; jj >>= 1) {
                    for (int i = tid; i < 2048; i += 512) {
                        const int ixj = i ^ jj;
                        if (ixj > i) {
                            const u64 a = keys[i], bb2 = keys[ixj];
                            const bool up = ((i & kk2) == 0);
                            if ((a > bb2) == up) { keys[i] = bb2; keys[ixj] = a; }
                        }
                    }
                    __syncthreads();
                }
            }
            if (tid < POST) {
                float* o = out + tid * 6;
                if (tid < target) {
                    const u64 key = ~keys[tid];
                    const int id = (int)(key & 0xFFFFull);
                    const float* rec = recs + (size_t)id * 8;
                    o[0] = rec[0]; o[1] = rec[1]; o[2] = rec[2]; o[3] = rec[3];
                    o[4] = __uint_as_float((unsigned)(key >> 32));
                    o[5] = (float)(id >> 9);
                } else {
                    o[0] = 0.f; o[1] = 0.f; o[2] = 0.f; o[3] = 0.f; o[4] = 0.f; o[5] = 0.f;
                }
            }
        }
        return;
    }

    // ---- per-wave redundant compaction (identical values -> benign LDS races) ----
    const int cls = (b >= SCAN0) ? (b - SCAN0) : (b >> 4);
    const float mycls = (float)cls;
    int myn = 0;
    for (int t0 = 0; t0 < PRE; t0 += 64) {
        const int t = t0 + lane;
        const bool pp = (t < PRE) && (x[t * 6 + 5] == mycls);
        const u64 mask = __ballot(pp);
        const int pos = myn + __popcll(mask & (((u64)1 << lane) - 1));
        if (pp && pos < CAP) s_list[pos] = (u16)t;
        myn += __popcll(mask);
    }
    if (myn > CAP) myn = CAP;

    // ================= MATRIX BLOCKS (0..79): 4 rows per wave =================
    if (b < SCAN0) {
        float qc0[8], qc1[8], qc2[8], qc3[8], ac[8];
        unrollN<8>([&](auto k_) {
            constexpr int K = decltype(k_)::v;
            const int c = K * 64 + lane;
            qc0[K] = 0.f; qc1[K] = 0.f; qc2[K] = 0.f; qc3[K] = 0.f; ac[K] = 0.f;
            if (c < myn) {
                const int g = s_list[c];
                const float* p = x + g * 6;
                const float b0 = p[0], b1 = p[1], b2 = p[2], b3 = p[3], sc = p[4];
                qc0[K] = (sc * b0) / sc; qc1[K] = (sc * b1) / sc;
                qc2[K] = (sc * b2) / sc; qc3[K] = (sc * b3) / sc;
                ac[K] = (qc2[K] - qc0[K]) * (qc3[K] - qc1[K]);
            }
        });
        const int rlo = (b & 15) * 32 + wave * 4;
        const int rhi = (rlo + 4 < myn) ? rlo + 4 : myn;
        for (int r = rlo; r < rhi; ++r) {
            const int g = s_list[r];
            const float* p = x + g * 6;
            const float bx0 = p[0], bx1 = p[1], bx2 = p[2], bx3 = p[3];
            const float a1 = (bx2 - bx0) * (bx3 - bx1);
            const int Wmax = r >> 6;   // words > Wmax have no bits c<r
            unrollN<8>([&](auto w_) {
                constexpr int W = decltype(w_)::v;
                if (W <= Wmax) {
                    const int c = W * 64 + lane;
                    const bool pred = (c < r) &&
                        iou_pred(bx0, bx1, bx2, bx3, a1, qc0[W], qc1[W], qc2[W], qc3[W], ac[W]);
                    const u64 bits = __ballot(pred);
                    if (lane == 0) M[((size_t)(cls * CAP + r)) * 8 + W] = bits;
                }
            });
        }
        __threadfence();
        if (lane == 0)   // one arrival per wave: target 16 blocks x 8 waves = 128
            __hip_atomic_fetch_add(&ctrl[cls], 1u, __ATOMIC_RELEASE, __HIP_MEMORY_SCOPE_AGENT);
        return;
    }

    // ================= SCAN BLOCKS (80..84) =================
    // Overlap with matrix phase: det preload (each wave owns rows wave*64+lane)
    {
        const int rr = wave * 64 + lane;
        if (rr < myn) {
            const int g = s_list[rr];
            const float* p = x + g * 6;
            const float b0 = p[0], b1 = p[1], b2 = p[2], b3 = p[3], sc = p[4];
            s_det[rr][0] = b0; s_det[rr][1] = b1; s_det[rr][2] = b2; s_det[rr][3] = b3;
            s_det[rr][4] = sc; s_det[rr][5] = (b2 - b0) * (b3 - b1);
            ((int*)s_det[rr])[6] = g;
        }
    }
    if (tid == 0) { while (aload_acq(&ctrl[cls]) < 128u) {} }
    __syncthreads();
    {   // 8-wave cooperative staging of the class matrix (32 KB)
        const ulonglong2* Mg = (const ulonglong2*)(M + (size_t)cls * CAP * 8);
        ulonglong2* Ml = (ulonglong2*)s_mtx;
        for (int it = tid; it < CAP * 4; it += 512) Ml[it] = Mg[it];
    }
    __syncthreads();
    if (wave != 0) return;   // no barriers after this point

    s_ab[lane] = 0;

    // scan state: lane L owns clean clusters 8L..8L+7; dirty clusters in s_dov rows
    u32 aliveB = 0;
    int dirtyCnt = 0;
    bool consA = false;
    int resCode = 0, resIdx = 0;

    auto resolve = [&](int r, u32 mC, u64 balC) {
        const float bx0 = s_det[r][0], bx1 = s_det[r][1];
        const float bx2 = s_det[r][2], bx3 = s_det[r][3];
        const float sc = s_det[r][4], a1 = s_det[r][5];
        int rank_c = INF;
        if (balC) {
            const int wl = (int)__builtin_ctzll(balC);
            const u32 byte = (u32)__builtin_amdgcn_readlane((int)mC, wl);
            rank_c = wl * 8 + (int)__builtin_ctz(byte);
        }
        int rank_d = INF, di = -1;
        if (dirtyCnt > 0) {
            bool p = false; int myrk = INF;
            if (lane < dirtyCnt) {
                const float* dv = s_dov[lane];
                p = iou_pred(bx0, bx1, bx2, bx3, a1, dv[0], dv[1], dv[2], dv[3], dv[4]);
                myrk = ((const int*)dv)[10];
            }
            u64 mk = __ballot(p);
            while (mk) {
                const int l = (int)__builtin_ctzll(mk);
                mk &= mk - 1;
                const int rk = __builtin_amdgcn_readlane(myrk, l);
                if (rk < rank_d) { rank_d = rk; di = l; }
            }
            for (int dd = 64; dd < dirtyCnt; ++dd) {
                const float* dv = s_dov[dd];
                if (iou_pred(bx0, bx1, bx2, bx3, a1, dv[0], dv[1], dv[2], dv[3], dv[4])) {
                    const int rk = ((const int*)dv)[10];
                    if (rk < rank_d) { rank_d = rk; di = dd; }
                }
            }
        }
        if (rank_c == INF && rank_d == INF) {
            aliveB |= ((r >> 3) == lane) ? (1u << (r & 7)) : 0u;
            resCode = 0;
        } else if (rank_c < rank_d) {
            const int rc = rank_c;
            aliveB &= ~(((rc >> 3) == lane) ? (1u << (rc & 7)) : 0u);
            const float cb0 = s_det[rc][0], cb1 = s_det[rc][1];
            const float cb2 = s_det[rc][2], cb3 = s_det[rc][3];
            const float csc = s_det[rc][4];
            const int cgi = ((const int*)s_det[rc])[6];
            // exact ref op order: solo sums fl(csc*cb), += fl(sc*bx), add, div
            const float ns0 = (csc * cb0) + sc * bx0;
            const float ns1 = (csc * cb1) + sc * bx1;
            const float ns2 = (csc * cb2) + sc * bx2;
            const float ns3 = (csc * cb3) + sc * bx3;
            const float nss = csc + sc;
            const float nm0 = ns0 / nss, nm1 = ns1 / nss;
            const float nm2 = ns2 / nss, nm3 = ns3 / nss;
            const int D = dirtyCnt;
            if (lane == 0 && D < 128) {
                float* dv = s_dov[D];
                dv[0] = nm0; dv[1] = nm1; dv[2] = nm2; dv[3] = nm3;
                dv[4] = (nm2 - nm0) * (nm3 - nm1);
                dv[5] = ns0; dv[6] = ns1; dv[7] = ns2; dv[8] = ns3; dv[9] = nss;
                ((int*)dv)[10] = rc; ((int*)dv)[11] = cgi; ((int*)dv)[12] = 2;
            }
            dirtyCnt++;
            resCode = 1; resIdx = D;
        } else {
            const float* dv = s_dov[di];
            const float f0 = dv[5] + sc * bx0, f1 = dv[6] + sc * bx1;
            const float f2 = dv[7] + sc * bx2, f3 = dv[8] + sc * bx3;
            const float fs = dv[9] + sc;
            const float nm0 = f0 / fs, nm1 = f1 / fs, nm2 = f2 / fs, nm3 = f3 / fs;
            const int nct = ((const int*)dv)[12] + 1;
            if (lane == 0) {
                float* dw = s_dov[di];
                dw[0] = nm0; dw[1] = nm1; dw[2] = nm2; dw[3] = nm3;
                dw[4] = (nm2 - nm0) * (nm3 - nm1);
                dw[5] = f0; dw[6] = f1; dw[7] = f2; dw[8] = f3; dw[9] = fs;
                ((int*)dw)[12] = nct;
            }
            resCode = 2; resIdx = di;
        }
    };

    // ---- batched scan: 64-det chunks, runs of guaranteed-creates skipped ----
    unrollN<8>([&](auto k_) {
        constexpr int K = decltype(k_)::v;
        const int r0 = K * 64;
        if (r0 < myn) {
            const int cnt = (myn - r0 < 64) ? (myn - r0) : 64;
            const bool valid = lane < cnt;
            const u64 validM = (cnt == 64) ? ~0ull : (((u64)1 << cnt) - 1ull);
            // tightened rowNE: prior-chunk words masked by alive image (chunk-start state)
            u64 orv = 0ull;
            {
                const int rr = r0 + (valid ? lane : 0);
                const u64* rp = (const u64*)&s_mtx[(size_t)rr * 64];
                const u64* av = (const u64*)s_ab;
                unrollN<8>([&](auto w_) {
                    constexpr int W = decltype(w_)::v;
                    if (W < K)       orv |= rp[W] & av[W];
                    else if (W == K) orv |= rp[W];
                });
            }
            const u64 rowW = __ballot(valid && orv != 0ull);
            float4 db = make_float4(0.f, 0.f, 0.f, 0.f);
            float2 de = make_float2(1.f, 0.f);
            if (valid) {
                db = *(const float4*)&s_det[r0 + lane][0];
                de = *(const float2*)&s_det[r0 + lane][4];
            }
            // dirty-match mask: bit d = my det matches dirty cluster d (exact)
            u64 dmask = 0ull;
            if (!consA) {
                const int DN = (dirtyCnt < 64) ? dirtyCnt : 64;
                for (int d = 0; d < DN; ++d) {
                    const float* dv = s_dov[d];
                    const bool pp = valid && iou_pred(db.x, db.y, db.z, db.w, de.y,
                                                     dv[0], dv[1], dv[2], dv[3], dv[4]);
                    if (pp) dmask |= 1ull << d;
                }
            }
            u64 danyb = __ballot(dmask != 0ull);
            int p = 0;
            while (p < cnt) {
                u64 vm = consA ? validM : ((danyb | rowW) & validM);
                vm &= ~(((u64)1 << p) - 1ull);
                const int F = vm ? (int)__builtin_ctzll(vm) : cnt;
                {   // commit creates [r0+p, r0+F): one masked OR per lane
                    const int lo = r0 + p, h2 = r0 + F;
                    int s = lo - 8 * lane; s = (s > 0) ? s : 0;
                    int e = h2 - 8 * lane; e = (e < 8) ? e : 8;
                    if (e > s) aliveB |= ((0xFFu >> (8 - (e - s))) << s);
                }
                if (F >= cnt) break;
                const int r = r0 + F;
                const u32 rowByte = (u32)s_mtx[(size_t)r * 64 + lane];
                const u32 mC = rowByte & aliveB;
                const u64 balC = __ballot(mC != 0u);
                const bool Fdirty = consA || (((danyb >> F) & 1ull) != 0ull);
                if (!Fdirty && balC == 0ull) {
                    aliveB |= ((r >> 3) == lane) ? (1u << (r & 7)) : 0u;   // create
                } else {
                    resolve(r, mC, balC);
                    if (resCode != 0) {
                        const int idx = resIdx;
                        if (idx < 64) {
                            const float* dv = s_dov[idx];
                            const bool pnew = valid && (lane > F) &&
                                iou_pred(db.x, db.y, db.z, db.w, de.y,
                                         dv[0], dv[1], dv[2], dv[3], dv[4]);
                            const u64 nb = __ballot(pnew);
                            dmask = (dmask & ~(1ull << idx)) | (((nb >> lane) & 1ull) << idx);
                            danyb = __ballot(dmask != 0ull);
                        } else {
                            consA = true;   // beyond mask capacity: exact-serial rest
                        }
                    }
                }
                p = F + 1;
            }
            s_ab[lane] = (u8)aliveB;   // alive image refresh: once per chunk
        }
    });

    // ---- emit compacted records: clean (solo mean, score=sc) then dirty ----
    int wo = 0;
    for (int Kw = 0; Kw < 8; ++Kw) {
        u64 am = 0ull;
        #pragma unroll
        for (int bb = 0; bb < 8; ++bb)
            am |= (u64)(u32)(u8)__builtin_amdgcn_readlane((int)aliveB, Kw * 8 + bb) << (8 * bb);
        const int j = Kw * 64 + lane;
        const bool pred = (am >> lane) & 1ull;
        if (pred) {
            const int pos = wo + (int)__popcll(am & (((u64)1 << lane) - 1));
            const float b0 = s_det[j][0], b1 = s_det[j][1];
            const float b2 = s_det[j][2], b3 = s_det[j][3];
            const float sc = s_det[j][4];
            const int g = ((const int*)s_det[j])[6];
            float* rec = recs + (size_t)(cls * CAP + pos) * 8;
            rec[0] = (sc * b0) / sc; rec[1] = (sc * b1) / sc;
            rec[2] = (sc * b2) / sc; rec[3] = (sc * b3) / sc;
            rec[4] = sc;
            ((int*)rec)[5] = g;
        }
        wo += (int)__popcll(am);
    }
    const int demit = (dirtyCnt < 128) ? dirtyCnt : 128;
    for (int d = lane; d < demit; d += 64) {
        const float* dv = s_dov[d];
        float* rec = recs + (size_t)(cls * CAP + wo + d) * 8;
        rec[0] = dv[0]; rec[1] = dv[1]; rec[2] = dv[2]; rec[3] = dv[3];
        rec[4] = dv[9] / (float)(((const int*)dv)[12]);   // exact IEEE div
        ((int*)rec)[5] = ((const int*)dv)[11];
    }
    if (lane == 0) cnts[cls] = wo + demit;
    __threadfence();
    if (lane == 0)
        __hip_atomic_fetch_add(&ctrl[16], 1u, __ATOMIC_RELEASE, __HIP_MEMORY_SCOPE_AGENT);
}

extern "C" void kernel_launch(void* const* d_in, const int* in_sizes, int n_in,
                              void* d_out, int out_size, void* d_ws, size_t ws_size,
                              hipStream_t stream) {
    const float* x = (const float*)d_in[0];
    float* out = (float*)d_out;
    // ws layout: M 160 KB | ctrl 256 B | cnts 256 B | recs 80 KB
    u64* M      = (u64*)d_ws;
    u32* ctrl   = (u32*)((char*)d_ws + (size_t)NCLS * CAP * 8 * 8);
    int* cnts   = (int*)((char*)d_ws + (size_t)NCLS * CAP * 8 * 8 + 256);
    float* recs = (float*)((char*)d_ws + (size_t)NCLS * CAP * 8 * 8 + 512);
    wbf_all<<<NBLK, 512, 0, stream>>>(x, M, ctrl, recs, cnts, out);
}